// Round 8
// baseline (193.409 us; speedup 1.0000x reference)
//
#include <hip/hip_runtime.h>
#include <hip/hip_bf16.h>

// CausalSelfAttention on MI355X (gfx950)
// x[4,2048,1024] f32, Wq/Wk/Wv/Wo [1024,1024] f32 -> out [4,2048,1024] f32
// Pipeline: cast->bf16, fused QKV GEMM (MFMA), flash attention, out-proj GEMM.

typedef __bf16 bf16_t;
typedef __bf16 bf16x4 __attribute__((ext_vector_type(4)));
typedef __bf16 bf16x8 __attribute__((ext_vector_type(8)));
typedef float  f32x4  __attribute__((ext_vector_type(4)));

#define MFMA16(a, b, c) __builtin_amdgcn_mfma_f32_16x16x32_bf16(a, b, c, 0, 0, 0)

__device__ __forceinline__ float exp2_(float x) {
#if __has_builtin(__builtin_amdgcn_exp2f)
    return __builtin_amdgcn_exp2f(x);
#else
    return __expf(x * 0.6931471805599453f);
#endif
}

__device__ __forceinline__ void gload_lds16(const bf16_t* g, bf16_t* l) {
    __builtin_amdgcn_global_load_lds(
        (const __attribute__((address_space(1))) void*)g,
        (__attribute__((address_space(3))) void*)l, 16, 0, 0);
}

// ---------------------------------------------------------------- casts
__global__ __launch_bounds__(256)
void cast_f32_bf16(const float* __restrict__ in, bf16_t* __restrict__ out, int n8) {
    int i = blockIdx.x * 256 + threadIdx.x;
    if (i >= n8) return;
    const float4* p = (const float4*)in;
    float4 a = p[i * 2], b = p[i * 2 + 1];
    bf16x8 o;
    o[0] = (bf16_t)a.x; o[1] = (bf16_t)a.y; o[2] = (bf16_t)a.z; o[3] = (bf16_t)a.w;
    o[4] = (bf16_t)b.x; o[5] = (bf16_t)b.y; o[6] = (bf16_t)b.z; o[7] = (bf16_t)b.w;
    *(bf16x8*)(out + (size_t)i * 8) = o;
}

__global__ __launch_bounds__(256)
void cast4_f32_bf16(const float* __restrict__ i0, const float* __restrict__ i1,
                    const float* __restrict__ i2, const float* __restrict__ i3,
                    bf16_t* o0, bf16_t* o1, bf16_t* o2, bf16_t* o3, int n8) {
    const float* in = blockIdx.y == 0 ? i0 : blockIdx.y == 1 ? i1 : blockIdx.y == 2 ? i2 : i3;
    bf16_t*     out = blockIdx.y == 0 ? o0 : blockIdx.y == 1 ? o1 : blockIdx.y == 2 ? o2 : o3;
    int i = blockIdx.x * 256 + threadIdx.x;
    if (i >= n8) return;
    const float4* p = (const float4*)in;
    float4 a = p[i * 2], b = p[i * 2 + 1];
    bf16x8 o;
    o[0] = (bf16_t)a.x; o[1] = (bf16_t)a.y; o[2] = (bf16_t)a.z; o[3] = (bf16_t)a.w;
    o[4] = (bf16_t)b.x; o[5] = (bf16_t)b.y; o[6] = (bf16_t)b.z; o[7] = (bf16_t)b.w;
    *(bf16x8*)(out + (size_t)i * 8) = o;
}

// ---------------------------------------------------------------- GEMM (C = A * B^T)
// m97 structure, DEFAULT block mapping: lin = bx + gx*by round-robins XCDs with
// bm ≡ xcd (mod 8) -> each XCD's 2MB A-slice stays L2-resident (measured: the
// R5 "contiguous chunk" swizzle forced A through every XCD = 172MB fetch, -33%).
template<int OUT_BF16>
__global__ __launch_bounds__(256)
void gemm_bt(const bf16_t* __restrict__ A, const bf16_t* __restrict__ B,
             void* __restrict__ Cv, int M, int N, int K) {
    __shared__ bf16_t As[128 * 32];
    __shared__ bf16_t Bs[128 * 32];
    const int tid = threadIdx.x;
    const int lane = tid & 63;
    const int w = tid >> 6;
    const int wm = w >> 1, wn = w & 1;
    const int g = lane >> 4, c = lane & 15;
    const long bm = (long)blockIdx.x * 128;
    const long bn = (long)blockIdx.y * 128;

    f32x4 acc[4][4] = {};

    const int srow = tid >> 2;
    const int scol = (tid & 3) << 3;
    const bf16_t* Ag = A + (bm + srow) * (long)K + scol;
    const bf16_t* Bg = B + (bn + srow) * (long)K + scol;
    bf16_t* AsW = As + tid * 8;
    bf16_t* BsW = Bs + tid * 8;

    for (int k0 = 0; k0 < K; k0 += 32) {
        gload_lds16(Ag + k0,                 AsW);
        gload_lds16(Ag + k0 + (long)64 * K,  AsW + 2048);
        gload_lds16(Bg + k0,                 BsW);
        gload_lds16(Bg + k0 + (long)64 * K,  BsW + 2048);
        __syncthreads();
        bf16x8 af[4], bfr[4];
        #pragma unroll
        for (int m = 0; m < 4; ++m)
            af[m] = *(const bf16x8*)(As + (wm * 64 + m * 16 + c) * 32 + g * 8);
        #pragma unroll
        for (int n = 0; n < 4; ++n)
            bfr[n] = *(const bf16x8*)(Bs + (wn * 64 + n * 16 + c) * 32 + g * 8);
        #pragma unroll
        for (int m = 0; m < 4; ++m)
            #pragma unroll
            for (int n = 0; n < 4; ++n)
                acc[m][n] = MFMA16(af[m], bfr[n], acc[m][n]);
        __syncthreads();
    }
    #pragma unroll
    for (int m = 0; m < 4; ++m)
        #pragma unroll
        for (int n = 0; n < 4; ++n)
            #pragma unroll
            for (int i = 0; i < 4; ++i) {
                long row = bm + wm * 64 + m * 16 + g * 4 + i;
                long col = bn + wn * 64 + n * 16 + c;
                float v = acc[m][n][i];
                if (OUT_BF16) ((bf16_t*)Cv)[row * N + col] = (bf16_t)v;
                else          ((float*)Cv)[row * N + col]  = v;
            }
}

// ---------------------------------------------------------------- flash attention
// grid: (64=B*H, 8), block 512 (8 waves x 32 q-rows = 256 q-rows = 1 q-tile).
// q0 = by<4 ? 7-by : by-4 -> round-robin pairs (7,0)(6,1)(5,2)(4,3) per CU =
// uniform 16 tile-units/CU-slot. Swapped QK^T (lane owns one q-row per m-frag),
// K/V frags reused across both m-MFMAs (halves LDS reads per q-row), in-lane
// softmax + defer-max, conflict-free V-transpose staging, setprio.

__device__ __forceinline__ void stage_K(const bf16_t* Kp, long rowb, int kb, int hcol,
                                        bf16_t* Kbuf, int tid) {
    int row = tid >> 3;                       // 0..63
    int lb  = (tid & 7) ^ (row & 7);          // pre-swizzled source -> linear LDS
    gload_lds16(Kp + (rowb + kb + row) * 3072 + hcol + lb * 8, Kbuf + tid * 8);
}

// V-transpose staging: thread owns 1 d-row x 8 keys. Loads: 8 coalesced d16
// reads (lane=d, 128B/wave/instr). Write: one b128; bank-quad = (d+kblk)%8 ->
// 8 consecutive lanes cover all 8 quads -> conflict-free at stride 72.
__device__ __forceinline__ bf16x8 load_V8(const bf16_t* Vp, long rowb, int kb,
                                          int hcol, int tid) {
    const int d  = tid & 63;
    const int k0 = (tid >> 6) * 8;
    bf16x8 v;
    #pragma unroll
    for (int j = 0; j < 8; ++j)
        v[j] = Vp[(rowb + kb + k0 + j) * 3072 + hcol + d];
    return v;
}

__device__ __forceinline__ void write_V8(bf16_t* Vbuf, int tid, bf16x8 v) {
    const int d  = tid & 63;
    const int k0 = (tid >> 6) * 8;
    *(bf16x8*)&Vbuf[d * 72 + k0] = v;
}

__global__ __launch_bounds__(512, 4)
void attn_kernel(const bf16_t* __restrict__ Qp, const bf16_t* __restrict__ Kp,
                 const bf16_t* __restrict__ Vp, bf16_t* __restrict__ O) {
    __shared__ bf16_t Ks[2][64 * 64];    // K[key][d], d-blocks XOR-swizzled by key&7
    __shared__ bf16_t Vts[2][64 * 72];   // V^T[d][key], stride 72
    __shared__ bf16_t PW[8][32 * 72];    // per-wave P[q][key], stride 72

    const int tid = threadIdx.x, lane = tid & 63, w = tid >> 6;
    const int g = lane >> 4, c = lane & 15;
    const int bh = blockIdx.x;                    // same-bh blocks share XCD (id%8)
    const int b = bh >> 4, h = bh & 15;
    const long rowb = (long)b * 2048;
    const int hcol = h * 64;
    const float QSCL = 0.18033688011112042f;      // 0.125 * log2(e)

    const int by = blockIdx.y;
    const int q0 = by < 4 ? 7 - by : by - 4;      // pair big+small per CU
    const int qlo = q0 * 256 + w * 32;            // this wave's 32 q-rows
    const int nkt = 4 * q0 + 4;

    // Q as B-fragments: lane holds Q[q = qlo+m*16+c][k = ks*32+g*8+j]
    bf16x8 qf[2][2];
    #pragma unroll
    for (int m = 0; m < 2; ++m)
        #pragma unroll
        for (int ks = 0; ks < 2; ++ks) {
            qf[m][ks] = *(const bf16x8*)(Qp + (rowb + qlo + m * 16 + c) * 3072 +
                                         hcol + ks * 32 + g * 8);
            #pragma unroll
            for (int j = 0; j < 8; ++j)
                qf[m][ks][j] = (bf16_t)((float)qf[m][ks][j] * QSCL);
        }

    float m_r[2] = {-1e30f, -1e30f};
    float l_r[2] = {0.f, 0.f};
    f32x4 acc[2][4] = {};                         // O^T: [m][d-blk nt], col q=c

    stage_K(Kp, rowb, 0, hcol, Ks[0], tid);
    write_V8(Vts[0], tid, load_V8(Vp, rowb, 0, hcol, tid));
    __syncthreads();

    for (int t = 0; t < nkt; ++t) {
        const int cur = t & 1;
        const int kb = t * 64;
        const bool pre = (t + 1 < nkt);
        bf16x8 vreg;
        if (pre) {
            stage_K(Kp, rowb, kb + 64, hcol, Ks[cur ^ 1], tid);
            vreg = load_V8(Vp, rowb, kb + 64, hcol, tid);
        }

        if (kb <= qlo + 31) {                     // skip fully-masked tiles (per-wave)
            // --- S^T = K Q^T: rows key = nt*16+g*4+i, col q = c (per m-frag)
            f32x4 sacc[2][4] = {};
            __builtin_amdgcn_s_setprio(1);
            #pragma unroll
            for (int nt = 0; nt < 4; ++nt) {
                const int row = nt * 16 + c;
                #pragma unroll
                for (int ks = 0; ks < 2; ++ks) {
                    bf16x8 kf = *(const bf16x8*)&Ks[cur][row * 64 +
                                    (((ks * 4 + g) ^ (c & 7)) * 8)];
                    sacc[0][nt] = MFMA16(kf, qf[0][ks], sacc[0][nt]);
                    sacc[1][nt] = MFMA16(kf, qf[1][ks], sacc[1][nt]);
                }
            }
            __builtin_amdgcn_s_setprio(0);
            if (kb + 63 > qlo) {                  // diagonal: causal mask
                #pragma unroll
                for (int m = 0; m < 2; ++m) {
                    const int q = qlo + m * 16 + c;
                    #pragma unroll
                    for (int nt = 0; nt < 4; ++nt)
                        #pragma unroll
                        for (int i = 0; i < 4; ++i) {
                            int key = kb + nt * 16 + g * 4 + i;
                            if (key > q) sacc[m][nt][i] = -1e30f;
                        }
                }
            }

            // --- online softmax with defer-max (THR=8 in log2 units)
            float mx[2];
            #pragma unroll
            for (int m = 0; m < 2; ++m) {
                float a0 = fmaxf(fmaxf(sacc[m][0][0], sacc[m][0][1]),
                                 fmaxf(sacc[m][0][2], sacc[m][0][3]));
                float a1 = fmaxf(fmaxf(sacc[m][1][0], sacc[m][1][1]),
                                 fmaxf(sacc[m][1][2], sacc[m][1][3]));
                float a2 = fmaxf(fmaxf(sacc[m][2][0], sacc[m][2][1]),
                                 fmaxf(sacc[m][2][2], sacc[m][2][3]));
                float a3 = fmaxf(fmaxf(sacc[m][3][0], sacc[m][3][1]),
                                 fmaxf(sacc[m][3][2], sacc[m][3][3]));
                float mm = fmaxf(fmaxf(a0, a1), fmaxf(a2, a3));
                mm = fmaxf(mm, __shfl_xor(mm, 16, 64));
                mm = fmaxf(mm, __shfl_xor(mm, 32, 64));
                mx[m] = mm;
            }
            if (__any(fmaxf(mx[0] - m_r[0], mx[1] - m_r[1]) > 8.f)) {
                #pragma unroll
                for (int m = 0; m < 2; ++m) {
                    float mnew = fmaxf(m_r[m], mx[m]);
                    float scl = exp2_(m_r[m] - mnew);
                    #pragma unroll
                    for (int nt = 0; nt < 4; ++nt)
                        acc[m][nt] *= scl;
                    l_r[m] *= scl;
                    m_r[m] = mnew;
                }
            }
            #pragma unroll
            for (int m = 0; m < 2; ++m) {
                float rsn[4];
                #pragma unroll
                for (int nt = 0; nt < 4; ++nt) {
                    #pragma unroll
                    for (int i = 0; i < 4; ++i)
                        sacc[m][nt][i] = exp2_(sacc[m][nt][i] - m_r[m]);
                    rsn[nt] = (sacc[m][nt][0] + sacc[m][nt][1]) +
                              (sacc[m][nt][2] + sacc[m][nt][3]);
                }
                float rs = (rsn[0] + rsn[1]) + (rsn[2] + rsn[3]);
                rs += __shfl_xor(rs, 16, 64);
                rs += __shfl_xor(rs, 32, 64);
                l_r[m] += rs;

                // --- P pack: lane holds 4 consecutive keys -> one b64 per nt
                #pragma unroll
                for (int nt = 0; nt < 4; ++nt) {
                    bf16x4 t4;
                    #pragma unroll
                    for (int i = 0; i < 4; ++i) t4[i] = (bf16_t)sacc[m][nt][i];
                    *(bf16x4*)&PW[w][(m * 16 + c) * 72 + nt * 16 + g * 4] = t4;
                }
            }

            // --- PV: O^T += V^T P^T (A = V^T frag reused for both m, wave-private)
            __builtin_amdgcn_s_setprio(1);
            #pragma unroll
            for (int ks = 0; ks < 2; ++ks) {
                bf16x8 pf0 = *(const bf16x8*)&PW[w][(c)      * 72 + ks * 32 + g * 8];
                bf16x8 pf1 = *(const bf16x8*)&PW[w][(16 + c) * 72 + ks * 32 + g * 8];
                #pragma unroll
                for (int nt = 0; nt < 4; ++nt) {
                    bf16x8 vf = *(const bf16x8*)&Vts[cur][(nt * 16 + c) * 72 +
                                                          ks * 32 + g * 8];
                    acc[0][nt] = MFMA16(vf, pf0, acc[0][nt]);
                    acc[1][nt] = MFMA16(vf, pf1, acc[1][nt]);
                }
            }
            __builtin_amdgcn_s_setprio(0);
        }

        if (pre) write_V8(Vts[cur ^ 1], tid, vreg);  // write-late (T14)
        __syncthreads();                             // single barrier per tile
    }

    // --- epilogue: O^T -> (wave-private LDS transpose) coalesced O rows
    #pragma unroll
    for (int m = 0; m < 2; ++m) {
        float rl = __builtin_amdgcn_rcpf(l_r[m]);
        #pragma unroll
        for (int nt = 0; nt < 4; ++nt) {
            bf16x4 t4;
            #pragma unroll
            for (int i = 0; i < 4; ++i) t4[i] = (bf16_t)(acc[m][nt][i] * rl);
            *(bf16x4*)&PW[w][(m * 16 + c) * 72 + nt * 16 + g * 4] = t4;
        }
    }
    #pragma unroll
    for (int p = 0; p < 4; ++p) {
        int row = p * 8 + (lane >> 3);
        int ch  = (lane & 7) * 8;
        bf16x8 v = *(const bf16x8*)&PW[w][row * 72 + ch];
        *(bf16x8*)&O[(rowb + qlo + row) * 1024 + hcol + ch] = v;
    }
}

// ---------------------------------------------------------------- launch
extern "C" void kernel_launch(void* const* d_in, const int* in_sizes, int n_in,
                              void* d_out, int out_size, void* d_ws, size_t ws_size,
                              hipStream_t stream) {
    const float* x  = (const float*)d_in[0];
    const float* Wq = (const float*)d_in[1];
    const float* Wk = (const float*)d_in[2];
    const float* Wv = (const float*)d_in[3];
    const float* Wo = (const float*)d_in[4];

    const int M = 8192;
    const int C = 1024;

    char* ws = (char*)d_ws;
    bf16_t* xb   = (bf16_t*)(ws);                          // 16 MB
    bf16_t* wqkv = (bf16_t*)(ws + ((size_t)16 << 20));     //  6 MB ([3072][1024])
    bf16_t* wob  = (bf16_t*)(ws + ((size_t)22 << 20));     //  2 MB
    bf16_t* qkv  = (bf16_t*)(ws + ((size_t)24 << 20));     // 48 MB ([8192][3072])
    bf16_t* aob  = (bf16_t*)(ws + ((size_t)72 << 20));     // 16 MB ([8192][1024])

    cast_f32_bf16<<<(M * C / 8) / 256, 256, 0, stream>>>(x, xb, M * C / 8);
    cast4_f32_bf16<<<dim3((C * C / 8) / 256, 4), 256, 0, stream>>>(
        Wq, Wk, Wv, Wo,
        wqkv, wqkv + (size_t)(C * C), wqkv + (size_t)(2 * C * C), wob, C * C / 8);

    gemm_bt<1><<<dim3(M / 128, 3072 / 128), 256, 0, stream>>>(xb, wqkv, qkv, M, 3072, C);

    attn_kernel<<<dim3(64, 8), 512, 0, stream>>>(
        qkv, qkv + 1024, qkv + 2048, aob);

    gemm_bt<0><<<dim3(M / 128, C / 128), 256, 0, stream>>>(aob, wob, d_out, M, C, C);
}

// Round 9
// 179.682 us; speedup vs baseline: 1.0764x; 1.0764x over previous
//
#include <hip/hip_runtime.h>
#include <hip/hip_bf16.h>

// CausalSelfAttention on MI355X (gfx950)
// x[4,2048,1024] f32, Wq/Wk/Wv/Wo [1024,1024] f32 -> out [4,2048,1024] f32
// Pipeline: cast->bf16, fused QKV GEMM (MFMA), flash attention, out-proj GEMM.

typedef __bf16 bf16_t;
typedef __bf16 bf16x4 __attribute__((ext_vector_type(4)));
typedef __bf16 bf16x8 __attribute__((ext_vector_type(8)));
typedef float  f32x4  __attribute__((ext_vector_type(4)));

#define MFMA16(a, b, c) __builtin_amdgcn_mfma_f32_16x16x32_bf16(a, b, c, 0, 0, 0)

__device__ __forceinline__ float exp2_(float x) {
#if __has_builtin(__builtin_amdgcn_exp2f)
    return __builtin_amdgcn_exp2f(x);
#else
    return __expf(x * 0.6931471805599453f);
#endif
}

__device__ __forceinline__ void gload_lds16(const bf16_t* g, bf16_t* l) {
    __builtin_amdgcn_global_load_lds(
        (const __attribute__((address_space(1))) void*)g,
        (__attribute__((address_space(3))) void*)l, 16, 0, 0);
}

// ---------------------------------------------------------------- cast (merged)
// y=0: x (1,048,576 chunks). y=1: Wq/Wk/Wv -> wqkv rows, Wo -> wob (524,288).
__global__ __launch_bounds__(256)
void cast_all(const float* __restrict__ x,  const float* __restrict__ Wq,
              const float* __restrict__ Wk, const float* __restrict__ Wv,
              const float* __restrict__ Wo,
              bf16_t* __restrict__ xb, bf16_t* __restrict__ wqkv,
              bf16_t* __restrict__ wob) {
    int i = blockIdx.x * 256 + threadIdx.x;
    const float* src;
    bf16_t* dst;
    if (blockIdx.y == 0) {
        src = x; dst = xb;
    } else {
        if (i >= 524288) return;
        int wsel = i >> 17;                 // 0..3
        int loc  = i & 131071;
        src = wsel == 0 ? Wq : wsel == 1 ? Wk : wsel == 2 ? Wv : Wo;
        dst = wsel == 3 ? wob : wqkv + (size_t)wsel * 1048576;
        i = loc;
    }
    const float4* p = (const float4*)src;
    float4 a = p[i * 2], b = p[i * 2 + 1];
    bf16x8 o;
    o[0] = (bf16_t)a.x; o[1] = (bf16_t)a.y; o[2] = (bf16_t)a.z; o[3] = (bf16_t)a.w;
    o[4] = (bf16_t)b.x; o[5] = (bf16_t)b.y; o[6] = (bf16_t)b.z; o[7] = (bf16_t)b.w;
    *(bf16x8*)(dst + (size_t)i * 8) = o;
}

// ---------------------------------------------------------------- GEMM (C = A * B^T)
// m97 structure, DEFAULT block mapping: lin = bx + gx*by round-robins XCDs with
// bm ≡ xcd (mod 8) -> each XCD's 2MB A-slice stays L2-resident (measured: the
// R5 "contiguous chunk" swizzle forced A through every XCD = 172MB fetch, -33%).
template<int OUT_BF16>
__global__ __launch_bounds__(256)
void gemm_bt(const bf16_t* __restrict__ A, const bf16_t* __restrict__ B,
             void* __restrict__ Cv, int M, int N, int K) {
    __shared__ bf16_t As[128 * 32];
    __shared__ bf16_t Bs[128 * 32];
    const int tid = threadIdx.x;
    const int lane = tid & 63;
    const int w = tid >> 6;
    const int wm = w >> 1, wn = w & 1;
    const int g = lane >> 4, c = lane & 15;
    const long bm = (long)blockIdx.x * 128;
    const long bn = (long)blockIdx.y * 128;

    f32x4 acc[4][4] = {};

    const int srow = tid >> 2;
    const int scol = (tid & 3) << 3;
    const bf16_t* Ag = A + (bm + srow) * (long)K + scol;
    const bf16_t* Bg = B + (bn + srow) * (long)K + scol;
    bf16_t* AsW = As + tid * 8;
    bf16_t* BsW = Bs + tid * 8;

    for (int k0 = 0; k0 < K; k0 += 32) {
        gload_lds16(Ag + k0,                 AsW);
        gload_lds16(Ag + k0 + (long)64 * K,  AsW + 2048);
        gload_lds16(Bg + k0,                 BsW);
        gload_lds16(Bg + k0 + (long)64 * K,  BsW + 2048);
        __syncthreads();
        bf16x8 af[4], bfr[4];
        #pragma unroll
        for (int m = 0; m < 4; ++m)
            af[m] = *(const bf16x8*)(As + (wm * 64 + m * 16 + c) * 32 + g * 8);
        #pragma unroll
        for (int n = 0; n < 4; ++n)
            bfr[n] = *(const bf16x8*)(Bs + (wn * 64 + n * 16 + c) * 32 + g * 8);
        #pragma unroll
        for (int m = 0; m < 4; ++m)
            #pragma unroll
            for (int n = 0; n < 4; ++n)
                acc[m][n] = MFMA16(af[m], bfr[n], acc[m][n]);
        __syncthreads();
    }
    #pragma unroll
    for (int m = 0; m < 4; ++m)
        #pragma unroll
        for (int n = 0; n < 4; ++n)
            #pragma unroll
            for (int i = 0; i < 4; ++i) {
                long row = bm + wm * 64 + m * 16 + g * 4 + i;
                long col = bn + wn * 64 + n * 16 + c;
                float v = acc[m][n][i];
                if (OUT_BF16) ((bf16_t*)Cv)[row * N + col] = (bf16_t)v;
                else          ((float*)Cv)[row * N + col]  = v;
            }
}

// ---------------------------------------------------------------- flash attention
// grid: (64=B*H, 16), block 512 (8 waves x 16 q-rows). q0 = 15-by (big first).
// Swapped QK^T (lane owns one q-row), defer-max with PER-LANE partial max/sum
// (cross-lane shfls only in the rare rescale branch + once in epilogue),
// conflict-free V-transpose staging, setprio.

__device__ __forceinline__ void stage_K(const bf16_t* Kp, long rowb, int kb, int hcol,
                                        bf16_t* Kbuf, int tid) {
    int row = tid >> 3;                       // 0..63
    int lb  = (tid & 7) ^ (row & 7);          // pre-swizzled source -> linear LDS
    gload_lds16(Kp + (rowb + kb + row) * 3072 + hcol + lb * 8, Kbuf + tid * 8);
}

// V-transpose staging: thread owns 1 d-row x 8 keys; b128 write at stride 72
// is bank-quad (d+kblk)%8 -> conflict-free.
__device__ __forceinline__ bf16x8 load_V8(const bf16_t* Vp, long rowb, int kb,
                                          int hcol, int tid) {
    const int d  = tid & 63;
    const int k0 = (tid >> 6) * 8;
    bf16x8 v;
    #pragma unroll
    for (int j = 0; j < 8; ++j)
        v[j] = Vp[(rowb + kb + k0 + j) * 3072 + hcol + d];
    return v;
}

__device__ __forceinline__ void write_V8(bf16_t* Vbuf, int tid, bf16x8 v) {
    const int d  = tid & 63;
    const int k0 = (tid >> 6) * 8;
    *(bf16x8*)&Vbuf[d * 72 + k0] = v;
}

__global__ __launch_bounds__(512, 6)
void attn_kernel(const bf16_t* __restrict__ Qp, const bf16_t* __restrict__ Kp,
                 const bf16_t* __restrict__ Vp, bf16_t* __restrict__ O) {
    __shared__ bf16_t Ks[2][64 * 64];    // K[key][d], d-blocks XOR-swizzled by key&7
    __shared__ bf16_t Vts[2][64 * 72];   // V^T[d][key], stride 72
    __shared__ bf16_t PW[8][16 * 72];    // per-wave P[q][key], stride 72

    const int tid = threadIdx.x, lane = tid & 63, w = tid >> 6;
    const int g = lane >> 4, c = lane & 15;
    const int bh = blockIdx.x;                    // same-bh blocks share XCD (id%8)
    const int b = bh >> 4, h = bh & 15;
    const long rowb = (long)b * 2048;
    const int hcol = h * 64;
    const float QSCL = 0.18033688011112042f;      // 0.125 * log2(e)

    const int q0  = 15 - blockIdx.y;              // biggest blocks first
    const int qlo = q0 * 128 + w * 16;            // this wave's 16 q-rows
    const int nkt = 2 * q0 + 2;

    // Q as B-fragments: lane holds Q[q = qlo+c][k = ks*32+g*8+j]
    bf16x8 qf[2];
    #pragma unroll
    for (int ks = 0; ks < 2; ++ks) {
        qf[ks] = *(const bf16x8*)(Qp + (rowb + qlo + c) * 3072 +
                                  hcol + ks * 32 + g * 8);
        #pragma unroll
        for (int j = 0; j < 8; ++j)
            qf[ks][j] = (bf16_t)((float)qf[ks][j] * QSCL);
    }

    float m_r = -1e30f;
    float l_r = 0.f;                              // PER-LANE partial sum
    f32x4 acc[4] = {};                            // O^T: [d-blk nt], rows g*4+i, col q=c

    stage_K(Kp, rowb, 0, hcol, Ks[0], tid);
    write_V8(Vts[0], tid, load_V8(Vp, rowb, 0, hcol, tid));
    __syncthreads();

    for (int t = 0; t < nkt; ++t) {
        const int cur = t & 1;
        const int kb = t * 64;
        const bool pre = (t + 1 < nkt);
        bf16x8 vreg;
        if (pre) {
            stage_K(Kp, rowb, kb + 64, hcol, Ks[cur ^ 1], tid);
            vreg = load_V8(Vp, rowb, kb + 64, hcol, tid);
        }

        if (kb <= qlo + 15) {                     // skip fully-masked tiles (per-wave)
            // --- S^T = K Q^T: rows key = nt*16+g*4+i, col q = c
            f32x4 sacc[4] = {};
            __builtin_amdgcn_s_setprio(1);
            #pragma unroll
            for (int nt = 0; nt < 4; ++nt) {
                const int row = nt * 16 + c;
                #pragma unroll
                for (int ks = 0; ks < 2; ++ks) {
                    bf16x8 kf = *(const bf16x8*)&Ks[cur][row * 64 +
                                    (((ks * 4 + g) ^ (c & 7)) * 8)];
                    sacc[nt] = MFMA16(kf, qf[ks], sacc[nt]);
                }
            }
            __builtin_amdgcn_s_setprio(0);
            if (kb + 63 > qlo) {                  // diagonal: causal mask
                const int q = qlo + c;
                #pragma unroll
                for (int nt = 0; nt < 4; ++nt)
                    #pragma unroll
                    for (int i = 0; i < 4; ++i) {
                        int key = kb + nt * 16 + g * 4 + i;
                        if (key > q) sacc[nt][i] = -1e30f;
                    }
            }

            // --- per-lane partial max (3-ary nests -> v_max3), no shfl here
            float m0 = fmaxf(fmaxf(sacc[0][0], sacc[0][1]),
                             fmaxf(fmaxf(sacc[0][2], sacc[0][3]), sacc[1][0]));
            float m1 = fmaxf(fmaxf(sacc[1][1], sacc[1][2]),
                             fmaxf(fmaxf(sacc[1][3], sacc[2][0]), sacc[2][1]));
            float m2 = fmaxf(fmaxf(sacc[2][2], sacc[2][3]),
                             fmaxf(fmaxf(sacc[3][0], sacc[3][1]),
                                   fmaxf(sacc[3][2], sacc[3][3])));
            float mx = fmaxf(fmaxf(m0, m1), m2);
            // defer-max: per-lane trigger is exact (any lane partial > thr
            // <=> group max > thr). Reduce only inside the rare branch.
            if (__any(mx > m_r + 8.f)) {
                mx = fmaxf(mx, __shfl_xor(mx, 16, 64));
                mx = fmaxf(mx, __shfl_xor(mx, 32, 64));
                float mnew = fmaxf(m_r, mx);
                float scl = exp2_(m_r - mnew);
                #pragma unroll
                for (int nt = 0; nt < 4; ++nt)
                    acc[nt] *= scl;
                l_r *= scl;
                m_r = mnew;
            }
            // --- exp + per-lane partial sum (no shfl)
            float rsn[4];
            #pragma unroll
            for (int nt = 0; nt < 4; ++nt) {
                #pragma unroll
                for (int i = 0; i < 4; ++i)
                    sacc[nt][i] = exp2_(sacc[nt][i] - m_r);
                rsn[nt] = (sacc[nt][0] + sacc[nt][1]) + (sacc[nt][2] + sacc[nt][3]);
            }
            l_r += (rsn[0] + rsn[1]) + (rsn[2] + rsn[3]);

            // --- P pack: lane holds 4 consecutive keys -> one b64 per nt
            #pragma unroll
            for (int nt = 0; nt < 4; ++nt) {
                bf16x4 t4;
                #pragma unroll
                for (int i = 0; i < 4; ++i) t4[i] = (bf16_t)sacc[nt][i];
                *(bf16x4*)&PW[w][c * 72 + nt * 16 + g * 4] = t4;
            }

            // --- PV: O^T += V^T P^T (A = V^T frag, B = P frag, wave-private)
            __builtin_amdgcn_s_setprio(1);
            #pragma unroll
            for (int ks = 0; ks < 2; ++ks) {
                bf16x8 pf = *(const bf16x8*)&PW[w][c * 72 + ks * 32 + g * 8];
                #pragma unroll
                for (int nt = 0; nt < 4; ++nt) {
                    bf16x8 vf = *(const bf16x8*)&Vts[cur][(nt * 16 + c) * 72 +
                                                          ks * 32 + g * 8];
                    acc[nt] = MFMA16(vf, pf, acc[nt]);
                }
            }
            __builtin_amdgcn_s_setprio(0);
        }

        if (pre) write_V8(Vts[cur ^ 1], tid, vreg);  // write-late (T14)
        __syncthreads();                             // single barrier per tile
    }

    // --- epilogue: reduce l over the 4 g-lanes ONCE, then transpose via LDS
    l_r += __shfl_xor(l_r, 16, 64);
    l_r += __shfl_xor(l_r, 32, 64);
    {
        float rl = __builtin_amdgcn_rcpf(l_r);
        #pragma unroll
        for (int nt = 0; nt < 4; ++nt) {
            bf16x4 t4;
            #pragma unroll
            for (int i = 0; i < 4; ++i) t4[i] = (bf16_t)(acc[nt][i] * rl);
            *(bf16x4*)&PW[w][c * 72 + nt * 16 + g * 4] = t4;
        }
    }
    #pragma unroll
    for (int p = 0; p < 2; ++p) {
        int row = p * 8 + (lane >> 3);
        int ch  = (lane & 7) * 8;
        bf16x8 v = *(const bf16x8*)&PW[w][row * 72 + ch];
        *(bf16x8*)&O[(rowb + qlo + row) * 1024 + hcol + ch] = v;
    }
}

// ---------------------------------------------------------------- launch
extern "C" void kernel_launch(void* const* d_in, const int* in_sizes, int n_in,
                              void* d_out, int out_size, void* d_ws, size_t ws_size,
                              hipStream_t stream) {
    const float* x  = (const float*)d_in[0];
    const float* Wq = (const float*)d_in[1];
    const float* Wk = (const float*)d_in[2];
    const float* Wv = (const float*)d_in[3];
    const float* Wo = (const float*)d_in[4];

    const int M = 8192;
    const int C = 1024;

    char* ws = (char*)d_ws;
    bf16_t* xb   = (bf16_t*)(ws);                          // 16 MB
    bf16_t* wqkv = (bf16_t*)(ws + ((size_t)16 << 20));     //  6 MB ([3072][1024])
    bf16_t* wob  = (bf16_t*)(ws + ((size_t)22 << 20));     //  2 MB
    bf16_t* qkv  = (bf16_t*)(ws + ((size_t)24 << 20));     // 48 MB ([8192][3072])
    bf16_t* aob  = (bf16_t*)(ws + ((size_t)72 << 20));     // 16 MB ([8192][1024])

    cast_all<<<dim3(4096, 2), 256, 0, stream>>>(x, Wq, Wk, Wv, Wo, xb, wqkv, wob);

    gemm_bt<1><<<dim3(M / 128, 3072 / 128), 256, 0, stream>>>(xb, wqkv, qkv, M, 3072, C);

    attn_kernel<<<dim3(64, 16), 512, 0, stream>>>(
        qkv, qkv + 1024, qkv + 2048, aob);

    gemm_bt<0><<<dim3(M / 128, C / 128), 256, 0, stream>>>(aob, wob, d_out, M, C, C);
}